// Round 7
// baseline (319.786 us; speedup 1.0000x reference)
//
#include <hip/hip_runtime.h>
#include <hip/hip_bf16.h>

// Problem constants (L,N,E,H,D) = (2048,4,512,8,64)
#define E_DIM 512
#define N_BATCH 4
#define L_SEQ 2048
#define N_HEADS 8
#define H_DIM 64
#define N_ROWS (L_SEQ * N_BATCH) /* 8192 */
#define EPS_F 1e-6f
#define SC_Q 0.18033688f  /* 0.125 * log2(e): scores come out in log2 space */

typedef __attribute__((ext_vector_type(8))) short bf16x8;
typedef __attribute__((ext_vector_type(8))) _Float16 f16x8;
typedef __attribute__((ext_vector_type(4))) float f32x4;
typedef __attribute__((ext_vector_type(16))) float f32x16;

__device__ __forceinline__ void split2(float f, __hip_bfloat16& h, __hip_bfloat16& l) {
  h = __float2bfloat16(f);
  l = __float2bfloat16(f - __bfloat162float(h));
}

__device__ __forceinline__ unsigned int packf16(float a, float b) {
  union { _Float16 h[2]; unsigned int u; } c;
  c.h[0] = (_Float16)a;  // RN casts: unbiased
  c.h[1] = (_Float16)b;
  return c.u;
}

// ---------------------------------------------------------------------------
// Kernel W: pre-split weights fp32 -> bf16 hi/lo.  (unchanged)
// ---------------------------------------------------------------------------
__global__ __launch_bounds__(256) void wconv_kernel(
    const float* __restrict__ wio, const float* __restrict__ wo,
    __hip_bfloat16* __restrict__ wiohi, __hip_bfloat16* __restrict__ wiolo,
    __hip_bfloat16* __restrict__ wohi, __hip_bfloat16* __restrict__ wolo) {
  const int g = blockIdx.x * 256 + threadIdx.x;
  const float* src;
  __hip_bfloat16 *dh, *dl;
  int i;
  if (g < 196608) { src = wio; dh = wiohi; dl = wiolo; i = g * 4; }
  else            { src = wo;  dh = wohi;  dl = wolo;  i = (g - 196608) * 4; }
  const float4 f = *(const float4*)(src + i);
  alignas(8) __hip_bfloat16 h[4], l[4];
  split2(f.x, h[0], l[0]); split2(f.y, h[1], l[1]);
  split2(f.z, h[2], l[2]); split2(f.w, h[3], l[3]);
  *(uint2*)(dh + i) = *(const uint2*)h;
  *(uint2*)(dl + i) = *(const uint2*)l;
}

// ---------------------------------------------------------------------------
// Kernel A: packed QKV projection via MFMA, hi/lo 2-pass (hh + lh).
// Q epilogue folds SC_Q, stores fp16 (n,h,l,d); K stores fp16 (n,h,l,d);
// V epilogue computes u = max(v+sh,eps)^p and writes u^T fp16 (n,h,d,l)
// DIRECTLY (scattered 2B stores; L2 merges partial lines) -- transp kernel
// is gone.
// ---------------------------------------------------------------------------
__global__ __launch_bounds__(256, 3) void proj_qkv_kernel(
    const float* __restrict__ xq, const float* __restrict__ xk,
    const float* __restrict__ xv, const __hip_bfloat16* __restrict__ whi,
    const float* __restrict__ bias, const float* __restrict__ pw,
    const float* __restrict__ sw,
    _Float16* __restrict__ qbuf, _Float16* __restrict__ kbuf,
    _Float16* __restrict__ uT) {
  __shared__ __hip_bfloat16 Xh[128][40];
  __shared__ __hip_bfloat16 Xl[128][40];
  __shared__ __hip_bfloat16 Wh[128][40];
  const int z = blockIdx.z;
  const int row0 = blockIdx.x * 128;
  const int col0 = blockIdx.y * 128;
  const float* __restrict__ xsrc = (z == 0) ? xq : (z == 1) ? xk : xv;
  const int tid = threadIdx.x;
  const int lane = tid & 63;
  const int wv = tid >> 6;
  const int lidx = lane & 15;
  const int quad = lane >> 4;
  const int srow = tid >> 1;
  const int scol = (tid & 1) * 16;

  f32x4 acc[2][8];
#pragma unroll
  for (int rt = 0; rt < 2; ++rt)
#pragma unroll
    for (int ct = 0; ct < 8; ++ct) acc[rt][ct] = (f32x4){0.f, 0.f, 0.f, 0.f};

  const int ar0 = wv * 32 + lidx;

  for (int kt = 0; kt < 16; ++kt) {
    const int k0 = kt * 32;
    {
      const float* xp = xsrc + (size_t)(row0 + srow) * E_DIM + k0 + scol;
      float f[16];
      *(float4*)&f[0]  = ((const float4*)xp)[0];
      *(float4*)&f[4]  = ((const float4*)xp)[1];
      *(float4*)&f[8]  = ((const float4*)xp)[2];
      *(float4*)&f[12] = ((const float4*)xp)[3];
      alignas(16) __hip_bfloat16 hi[16], lo[16];
#pragma unroll
      for (int j = 0; j < 16; ++j) split2(f[j], hi[j], lo[j]);
      *(uint4*)&Xh[srow][scol]     = ((const uint4*)hi)[0];
      *(uint4*)&Xh[srow][scol + 8] = ((const uint4*)hi)[1];
      *(uint4*)&Xl[srow][scol]     = ((const uint4*)lo)[0];
      *(uint4*)&Xl[srow][scol + 8] = ((const uint4*)lo)[1];
    }
    {
      const size_t wof = (size_t)(z * E_DIM + col0 + srow) * E_DIM + k0 + scol;
      *(uint4*)&Wh[srow][scol]     = ((const uint4*)(whi + wof))[0];
      *(uint4*)&Wh[srow][scol + 8] = ((const uint4*)(whi + wof))[1];
    }
    __syncthreads();

    const bf16x8 ah0 = *(const bf16x8*)&Xh[ar0][quad * 8];
    const bf16x8 ah1 = *(const bf16x8*)&Xh[ar0 + 16][quad * 8];
    const bf16x8 al0 = *(const bf16x8*)&Xl[ar0][quad * 8];
    const bf16x8 al1 = *(const bf16x8*)&Xl[ar0 + 16][quad * 8];
#pragma unroll
    for (int ct = 0; ct < 8; ++ct) {
      const bf16x8 bh = *(const bf16x8*)&Wh[ct * 16 + lidx][quad * 8];
      acc[0][ct] = __builtin_amdgcn_mfma_f32_16x16x32_bf16(ah0, bh, acc[0][ct], 0, 0, 0);
      acc[0][ct] = __builtin_amdgcn_mfma_f32_16x16x32_bf16(al0, bh, acc[0][ct], 0, 0, 0);
      acc[1][ct] = __builtin_amdgcn_mfma_f32_16x16x32_bf16(ah1, bh, acc[1][ct], 0, 0, 0);
      acc[1][ct] = __builtin_amdgcn_mfma_f32_16x16x32_bf16(al1, bh, acc[1][ct], 0, 0, 0);
    }
    __syncthreads();
  }

  if (z < 2) {
    _Float16* __restrict__ dst = (z == 0) ? qbuf : kbuf;
    const float scale = (z == 0) ? SC_Q : 1.0f;
    float bv[8];
#pragma unroll
    for (int ct = 0; ct < 8; ++ct) bv[ct] = bias[z * E_DIM + col0 + ct * 16 + lidx];
#pragma unroll
    for (int rt = 0; rt < 2; ++rt)
#pragma unroll
      for (int ct = 0; ct < 8; ++ct) {
        const int e = col0 + ct * 16 + lidx;
        const int h = e >> 6, d = e & 63;
#pragma unroll
        for (int reg = 0; reg < 4; ++reg) {
          const int R = row0 + wv * 32 + rt * 16 + quad * 4 + reg;
          const int lpos = R >> 2, nb = R & 3;
          dst[(((size_t)nb * N_HEADS + h) * L_SEQ + lpos) * H_DIM + d] =
              (_Float16)((acc[rt][ct][reg] + bv[ct]) * scale);
        }
      }
  } else {
    float bv[8], pv[8], sv[8];
#pragma unroll
    for (int ct = 0; ct < 8; ++ct) {
      const int e = col0 + ct * 16 + lidx;
      bv[ct] = bias[2 * E_DIM + e]; pv[ct] = pw[e]; sv[ct] = sw[e];
    }
    // u^T direct: R = row0+wv*32+rt*16+quad*4+reg -> nb=reg, lpos=R>>2
    const int lposb = (row0 >> 2) + wv * 8;
#pragma unroll
    for (int rt = 0; rt < 2; ++rt)
#pragma unroll
      for (int ct = 0; ct < 8; ++ct) {
        const int e = col0 + ct * 16 + lidx;
        const int h = e >> 6, d = e & 63;
        const int lpos = lposb + rt * 4 + quad;
#pragma unroll
        for (int reg = 0; reg < 4; ++reg) {
          const float y = acc[rt][ct][reg] + bv[ct];
          const float vp = fmaxf(y + sv[ct], EPS_F);
          uT[(((size_t)reg * N_HEADS + h) * H_DIM + d) * L_SEQ + lpos] =
              (_Float16)__powf(vp, pv[ct]);
        }
      }
  }
}

// ---------------------------------------------------------------------------
// Kernel B: fp16 MFMA flash attention -- ZERO LDS, ZERO barriers.
// One wave per block (64 thr); 32 q/wave; S^T orientation (A=K, B=Q) so P
// stays in registers in B-operand layout (q = lane&31); one shfl_xor(32)
// per kc converts C->B frags.  K and U fragments load DIRECTLY from global:
// each frag row is a fully-consumed 128B L2 line (K head 256 KB + uT head
// slice are L2-resident).  Fixed-max softmax p = exp2(score) (scale folded
// into q).  Grid 64x8x4 = 2048 waves = 2/SIMD + 16-deep MLP per iter.
// ---------------------------------------------------------------------------
__global__ __launch_bounds__(64, 2) void attn_kernel(
    const _Float16* __restrict__ qbuf, const _Float16* __restrict__ kbuf,
    const _Float16* __restrict__ uT, const float* __restrict__ pw,
    const float* __restrict__ sw, __hip_bfloat16* __restrict__ ohhi,
    __hip_bfloat16* __restrict__ ohlo) {
  const int qt = blockIdx.x, h = blockIdx.y, nb = blockIdx.z;
  const int q0 = qt * 32;
  const int lane = threadIdx.x;
  const int lm = lane & 31;
  const int kg = lane >> 5;
  const size_t headbase = ((size_t)nb * N_HEADS + h) * L_SEQ;
  const size_t dbase = ((size_t)nb * N_HEADS + h) * H_DIM;

  // Q B-frags hoisted for the whole loop (q = q0 + lm)
  f16x8 bq[4];
#pragma unroll
  for (int kc = 0; kc < 4; ++kc)
    bq[kc] = *(const f16x8*)(qbuf + (headbase + q0 + lm) * H_DIM + kc * 16 + kg * 8);

  f32x16 o[2];
  o[0] = (f32x16)(0.f); o[1] = (f32x16)(0.f);
  float lsum = 0.f;

  for (int scn = 0; scn < 32; ++scn) {
    const int s0 = scn * 64;
    const _Float16* k0p = kbuf + (headbase + s0 + lm) * H_DIM;
    const _Float16* k1p = kbuf + (headbase + s0 + 32 + lm) * H_DIM;

    // ---- S^T: C-layout col = q (lane&31), rows = s ----
    f32x16 sc0 = (f32x16)(0.f), sc1 = (f32x16)(0.f);
#pragma unroll
    for (int kc = 0; kc < 4; ++kc) {
      const f16x8 ak0 = *(const f16x8*)(k0p + kc * 16 + kg * 8);
      const f16x8 ak1 = *(const f16x8*)(k1p + kc * 16 + kg * 8);
      sc0 = __builtin_amdgcn_mfma_f32_32x32x16_f16(ak0, bq[kc], sc0, 0, 0, 0);
      sc1 = __builtin_amdgcn_mfma_f32_32x32x16_f16(ak1, bq[kc], sc1, 0, 0, 0);
    }

    // ---- p = exp2(score); pack fp16 pairs; per-lane l partial ----
    unsigned int P2[2][4][2];
#pragma unroll
    for (int mt = 0; mt < 2; ++mt) {
      const f32x16 s = mt ? sc1 : sc0;
#pragma unroll
      for (int g = 0; g < 4; ++g) {
        const float p0 = __builtin_amdgcn_exp2f(s[4 * g + 0]);
        const float p1 = __builtin_amdgcn_exp2f(s[4 * g + 1]);
        const float p2 = __builtin_amdgcn_exp2f(s[4 * g + 2]);
        const float p3 = __builtin_amdgcn_exp2f(s[4 * g + 3]);
        lsum += (p0 + p1) + (p2 + p3);
        P2[mt][g][0] = packf16(p0, p1);
        P2[mt][g][1] = packf16(p2, p3);
      }
    }

    // ---- PV: O^T += U^T @ P^T; P B-frags via xor-32 exchange ----
    const _Float16* u0p = uT + (dbase + lm) * L_SEQ + s0;
    const _Float16* u1p = uT + (dbase + 32 + lm) * L_SEQ + s0;
#pragma unroll
    for (int kc = 0; kc < 4; ++kc) {
      const int mt = kc >> 1;
      const f16x8 au0 = *(const f16x8*)(u0p + kc * 16 + kg * 8);
      const f16x8 au1 = *(const f16x8*)(u1p + kc * 16 + kg * 8);
      const int gx = (2 * kc) & 3, gy = (2 * kc + 1) & 3;
      const unsigned int x0 = P2[mt][gx][0], x1 = P2[mt][gx][1];
      const unsigned int y0 = P2[mt][gy][0], y1 = P2[mt][gy][1];
      const unsigned int sA = kg ? x0 : y0, sB = kg ? x1 : y1;
      const unsigned int rA = (unsigned int)__shfl_xor((int)sA, 32);
      const unsigned int rB = (unsigned int)__shfl_xor((int)sB, 32);
      union { unsigned int u[4]; f16x8 v; } bp;
      bp.u[0] = kg ? rA : x0;
      bp.u[1] = kg ? rB : x1;
      bp.u[2] = kg ? y0 : rA;
      bp.u[3] = kg ? y1 : rB;
      o[0] = __builtin_amdgcn_mfma_f32_32x32x16_f16(au0, bp.v, o[0], 0, 0, 0);
      o[1] = __builtin_amdgcn_mfma_f32_32x32x16_f16(au1, bp.v, o[1], 0, 0, 0);
    }
  }

  // ---- epilogue: finish l across kg halves, GeM inverse, packed stores ----
  const float l = lsum + __shfl_xor(lsum, 32);
  const float inv = 1.0f / l;
  const int qg = q0 + lm;
  const size_t base = ((size_t)qg * N_BATCH + nb) * E_DIM + h * H_DIM;
#pragma unroll
  for (int mt2 = 0; mt2 < 2; ++mt2)
#pragma unroll
    for (int g = 0; g < 4; ++g) {
      alignas(8) __hip_bfloat16 hb[4], lb[4];
#pragma unroll
      for (int i = 0; i < 4; ++i) {
        const int d = mt2 * 32 + 8 * g + 4 * kg + i;
        const int e = h * H_DIM + d;
        const float pooled = o[mt2][4 * g + i] * inv;
        const float val = __powf(fmaxf(pooled, EPS_F), 1.0f / pw[e]) - sw[e];
        split2(val, hb[i], lb[i]);
      }
      const int d0 = mt2 * 32 + 8 * g + 4 * kg;
      *(uint2*)(ohhi + base + d0) = *(const uint2*)hb;
      *(uint2*)(ohlo + base + d0) = *(const uint2*)lb;
    }
}

// ---------------------------------------------------------------------------
// Kernel C: output projection via MFMA, hi/lo 3-pass.  (unchanged)
// ---------------------------------------------------------------------------
__global__ __launch_bounds__(256, 4) void out_proj_kernel(
    const __hip_bfloat16* __restrict__ xhi, const __hip_bfloat16* __restrict__ xlo,
    const __hip_bfloat16* __restrict__ whi, const __hip_bfloat16* __restrict__ wlo,
    const float* __restrict__ bias, float* __restrict__ out) {
  __shared__ __hip_bfloat16 Xh[128][40];
  __shared__ __hip_bfloat16 Xl[128][40];
  __shared__ __hip_bfloat16 Wh[64][40];
  __shared__ __hip_bfloat16 Wl[64][40];
  const int row0 = blockIdx.x * 128;
  const int col0 = blockIdx.y * 64;
  const int tid = threadIdx.x;
  const int lane = tid & 63;
  const int wv = tid >> 6;
  const int lidx = lane & 15;
  const int quad = lane >> 4;
  const int srow = tid >> 1;
  const int scol = (tid & 1) * 16;
  const int wrow = tid >> 2;
  const int wcol = (tid & 3) * 8;

  f32x4 acc[2][4];
#pragma unroll
  for (int rt = 0; rt < 2; ++rt)
#pragma unroll
    for (int ct = 0; ct < 4; ++ct) acc[rt][ct] = (f32x4){0.f, 0.f, 0.f, 0.f};

  const int ar0 = wv * 32 + lidx;

  for (int kt = 0; kt < 16; ++kt) {
    const int k0 = kt * 32;
    {
      const size_t xof = (size_t)(row0 + srow) * E_DIM + k0 + scol;
      *(uint4*)&Xh[srow][scol]     = ((const uint4*)(xhi + xof))[0];
      *(uint4*)&Xh[srow][scol + 8] = ((const uint4*)(xhi + xof))[1];
      *(uint4*)&Xl[srow][scol]     = ((const uint4*)(xlo + xof))[0];
      *(uint4*)&Xl[srow][scol + 8] = ((const uint4*)(xlo + xof))[1];
      const size_t wof = (size_t)(col0 + wrow) * E_DIM + k0 + wcol;
      *(uint4*)&Wh[wrow][wcol] = *(const uint4*)(whi + wof);
      *(uint4*)&Wl[wrow][wcol] = *(const uint4*)(wlo + wof);
    }
    __syncthreads();

    const bf16x8 ah0 = *(const bf16x8*)&Xh[ar0][quad * 8];
    const bf16x8 ah1 = *(const bf16x8*)&Xh[ar0 + 16][quad * 8];
    const bf16x8 al0 = *(const bf16x8*)&Xl[ar0][quad * 8];
    const bf16x8 al1 = *(const bf16x8*)&Xl[ar0 + 16][quad * 8];
#pragma unroll
    for (int ct = 0; ct < 4; ++ct) {
      const bf16x8 bh = *(const bf16x8*)&Wh[ct * 16 + lidx][quad * 8];
      const bf16x8 bl = *(const bf16x8*)&Wl[ct * 16 + lidx][quad * 8];
      acc[0][ct] = __builtin_amdgcn_mfma_f32_16x16x32_bf16(ah0, bh, acc[0][ct], 0, 0, 0);
      acc[0][ct] = __builtin_amdgcn_mfma_f32_16x16x32_bf16(al0, bh, acc[0][ct], 0, 0, 0);
      acc[0][ct] = __builtin_amdgcn_mfma_f32_16x16x32_bf16(ah0, bl, acc[0][ct], 0, 0, 0);
      acc[1][ct] = __builtin_amdgcn_mfma_f32_16x16x32_bf16(ah1, bh, acc[1][ct], 0, 0, 0);
      acc[1][ct] = __builtin_amdgcn_mfma_f32_16x16x32_bf16(al1, bh, acc[1][ct], 0, 0, 0);
      acc[1][ct] = __builtin_amdgcn_mfma_f32_16x16x32_bf16(ah1, bl, acc[1][ct], 0, 0, 0);
    }
    __syncthreads();
  }

  float bv[4];
#pragma unroll
  for (int ct = 0; ct < 4; ++ct) bv[ct] = bias[col0 + ct * 16 + lidx];
#pragma unroll
  for (int rt = 0; rt < 2; ++rt)
#pragma unroll
    for (int ct = 0; ct < 4; ++ct) {
      const int c = col0 + ct * 16 + lidx;
#pragma unroll
      for (int reg = 0; reg < 4; ++reg) {
        const int R = row0 + wv * 32 + rt * 16 + quad * 4 + reg;
        out[(size_t)R * E_DIM + c] = acc[rt][ct][reg] + bv[ct];
      }
    }
}

extern "C" void kernel_launch(void* const* d_in, const int* in_sizes, int n_in,
                              void* d_out, int out_size, void* d_ws, size_t ws_size,
                              hipStream_t stream) {
  const float* q_in = (const float*)d_in[0];
  const float* k_in = (const float*)d_in[1];
  const float* v_in = (const float*)d_in[2];
  const float* wio  = (const float*)d_in[3];
  const float* bio  = (const float*)d_in[4];
  const float* wo   = (const float*)d_in[5];
  const float* bo   = (const float*)d_in[6];
  const float* pw   = (const float*)d_in[7];
  const float* sw   = (const float*)d_in[8];

  // Workspace (~44 MiB): qbuf,kbuf f16 8 MiB ea; oh hi/lo bf16 8+8 MiB;
  // uT f16 8 MiB; weight splits ~4 MiB.  (ubuf + transp are gone.)
  const size_t NE = (size_t)N_ROWS * E_DIM;
  _Float16* qbuf = (_Float16*)d_ws;
  _Float16* kbuf = qbuf + NE;
  __hip_bfloat16* ohhi = (__hip_bfloat16*)(kbuf + NE);
  __hip_bfloat16* ohlo = ohhi + NE;
  _Float16* uT = (_Float16*)(ohlo + NE);
  __hip_bfloat16* wiohi = (__hip_bfloat16*)(uT + NE);
  __hip_bfloat16* wiolo = wiohi + 786432;
  __hip_bfloat16* wohi  = wiolo + 786432;
  __hip_bfloat16* wolo  = wohi + 262144;

  wconv_kernel<<<dim3(1024), 256, 0, stream>>>(wio, wo, wiohi, wiolo, wohi, wolo);
  proj_qkv_kernel<<<dim3(64, 4, 3), 256, 0, stream>>>(q_in, k_in, v_in, wiohi,
                                                      bio, pw, sw, qbuf, kbuf, uT);
  attn_kernel<<<dim3(64, 8, 4), 64, 0, stream>>>(qbuf, kbuf, uT, pw, sw,
                                                 ohhi, ohlo);
  out_proj_kernel<<<dim3(64, 8), 256, 0, stream>>>(ohhi, ohlo, wohi, wolo,
                                                   bo, (float*)d_out);
}